// Round 5
// baseline (545.523 us; speedup 1.0000x reference)
//
#include <hip/hip_runtime.h>

// VQ-VAE codebook quantization, MI355X (gfx950)
// z: [32, 256, 32, 32] fp32 ; codebook: [1024, 256] fp32
// outputs (concat fp32): z_q [32,256,32,32] (8388608) | idx [32768] | loss [1]
//
// Correctness contract: idx must match numpy's fp32 argmin of
//   dist = fl( fl(znorm + enorm) - 2*dot ),  ties -> lowest index.
// The +znorm(~256) term quantizes dist to ulp ~3e-5; replicating that
// quantization (NOT dropping the constant term) is what makes ties match.
//
// R2-R4 post-mortem: the 16m x 8k tile needs ~212 VGPRs but every knob
// (launch_bounds, waves_per_eu) left the allocator at 128 -> scratch spill
// (WRITE 33->53GB), 293-296us. Hard budget is 128 VGPRs.
// R5: go back to the spill-free 8m x 8k tile but fix R1's real costs:
//  - MT=64, 512 blocks -> TWO blocks/CU (74240B LDS each, 148480<=160K):
//    4 waves/SIMD of independent TLP hides barriers/staging stalls.
//  - wave-uniform a-reads (broadcast), contiguous 64-lane e-reads
//    (conflict-free), stride-1 staging writes (2/bank, free).
//  - Es single-buffer [4][512], async-split global prefetch between syncs.

#define D_DIM   256
#define K_CODES 1024
#define HW      1024
#define MT      64      // positions per block
#define NT      512     // codes per N-chunk (2 chunks)
#define BK      4       // d-rows staged per step
#define THREADS 512
#define NSTEP   128     // 2 chunks * 64 steps

#define ZQ_OFF   0
#define IDX_OFF  8388608
#define LOSS_OFF 8421376

// As[256][64] + Es[4][512] + znorm_s[64] + bestm[64]
#define SMEM_FLOATS (D_DIM*MT + BK*NT + MT + MT)   // 16384+2048+64+64 = 18560
#define SMEM_BYTES  (SMEM_FLOATS * 4)              // 74240 B ; x2 blocks = 148480 <= 163840

extern __shared__ float smem[];

// ws: enorm[k] = fp32 sum of cb[k][d]^2 (own order; ~ulp(8e-5) agreement is enough)
__global__ void enorm_kernel(const float* __restrict__ cb, float* __restrict__ enorm) {
    int gt = blockIdx.x * blockDim.x + threadIdx.x;
    int k = gt >> 6;
    int lane = gt & 63;
    const float4* row = (const float4*)(cb + (size_t)k * D_DIM);
    float4 v = row[lane];
    float s = fmaf(v.x, v.x, fmaf(v.y, v.y, fmaf(v.z, v.z, v.w * v.w)));
    #pragma unroll
    for (int off = 32; off; off >>= 1) s += __shfl_xor(s, off);
    if (lane == 0) enorm[k] = s;
}

__global__ __launch_bounds__(THREADS, 4)   // pin 4 waves/EU -> 128-reg budget, 2 blocks/CU
void vq_kernel(
        const float* __restrict__ z, const float* __restrict__ cb,
        const float* __restrict__ enorm, float* __restrict__ out)
{
    float* As = smem;                                   // [256][64]
    float* Es = smem + D_DIM * MT;                      // [4][512] (8KB; also znorm scratch)
    float* znorm_s = smem + D_DIM * MT + BK * NT;       // [64]
    int*   bestm   = (int*)(smem + D_DIM * MT + BK * NT + MT); // [64]

    const int t   = threadIdx.x;
    const int blk = blockIdx.x;          // 512 blocks = 2/CU
    const int b   = blk >> 4;
    const int p0  = (blk & 15) * MT;
    const float* zb = z + (size_t)b * D_DIM * HW;

    // staging: thread t stages code (chunk*512 + t), 4 d-values per step.
    const float* cbp = cb + (size_t)t * D_DIM;

    // prologue global load for step g=0 (issued early, hides under znorm)
    float4 sv = *(const float4*)(cbp);

    // ---- stage A^T [256][64] (z read from HBM once, coalesced float4) ----
    for (int i = t; i < D_DIM * MT / 4; i += THREADS) {
        int d = i >> 4, m4 = i & 15;
        *(float4*)(As + d * MT + m4 * 4) = *(const float4*)(zb + d * HW + p0 + m4 * 4);
    }
    __syncthreads();

    // ---- znorm[m] = fp64 sum of As[:,m]^2, rounded to fp32 ----
    // (fp64 vs numpy's pairwise-fp32 differs by <=1-2 ulp of ~256; that's a
    //  uniform exact-ulp shift per row -> argmin invariant.)
    {
        int m = t & (MT - 1), q = t >> 6;            // 8 slices of 32 d
        const float* col = As + m;
        double zp = 0.0;
        #pragma unroll 8
        for (int d = q * 32; d < q * 32 + 32; ++d) {
            double v = (double)col[d * MT];
            zp += v * v;
        }
        double* zscr = (double*)Es;                  // 512 doubles = 4 KB scratch
        zscr[q * MT + m] = zp;
    }
    __syncthreads();
    if (t < MT) {
        double* zscr = (double*)Es;
        double s = 0.0;
        #pragma unroll
        for (int q = 0; q < 8; ++q) s += zscr[q * MT + t];
        znorm_s[t] = (float)s;
    }
    // (first loop barrier below makes znorm_s visible & zscr reads complete
    //  before Es is overwritten by staging)

    // ---- thread layout: wave w owns m rows w*8..+7 (wave-uniform a-reads);
    //      lane tx owns codes {tx*4..+3} u {256+tx*4..+3} of each 512-chunk.
    const int tx = t & 63;
    const int m_base = (t >> 6) * 8;
    const int kx4 = tx * 4;

    float bestv[8]; int besti[8];
    #pragma unroll
    for (int i = 0; i < 8; ++i) { bestv[i] = 3.4e38f; besti[i] = 0; }

    float acc[8][8];
    #pragma unroll
    for (int i = 0; i < 8; ++i)
        #pragma unroll
        for (int j = 0; j < 8; ++j) acc[i][j] = 0.f;

    for (int g = 0; g < NSTEP; ++g) {
        const int c = g >> 6, s = g & 63;

        __syncthreads();                 // readers of previous Es done
        Es[0 * NT + t] = sv.x;           // stride-1 across lanes: 2/bank, free
        Es[1 * NT + t] = sv.y;
        Es[2 * NT + t] = sv.z;
        Es[3 * NT + t] = sv.w;

        // issue next-step global load (L2 latency hides under 4 dd-groups of FMA)
        {
            const int gn = (g < NSTEP - 1) ? g + 1 : NSTEP - 1;
            sv = *(const float4*)(cbp + (((size_t)(gn >> 6)) << 17) + ((gn & 63) << 2));
        }
        __syncthreads();                 // Es visible

        const int dk = s * BK;
        #pragma unroll
        for (int dd = 0; dd < BK; ++dd) {
            const float* Ar = As + (dk + dd) * MT + m_base;   // wave-uniform bcast
            float a[8], e[8];
            *(float4*)(a)     = *(const float4*)(Ar);
            *(float4*)(a + 4) = *(const float4*)(Ar + 4);
            const float* Er = Es + dd * NT + kx4;
            *(float4*)(e)     = *(const float4*)(Er);         // codes kx4..+3
            *(float4*)(e + 4) = *(const float4*)(Er + 256);   // codes 256+kx4..+3
            #pragma unroll
            for (int i = 0; i < 8; ++i)
                #pragma unroll
                for (int j = 0; j < 8; ++j)
                    acc[i][j] = fmaf(a[i], e[j], acc[i][j]);
        }

        if (s == 63) {
            // chunk epilogue: dist = fl( fl(znorm + enorm) - 2*dot ), np-style
            // lane's j=0..3 -> codes c*512+kx4+j ; j=4..7 -> c*512+256+kx4+(j-4)
            #pragma unroll
            for (int j = 0; j < 8; ++j) {
                const int kidx = c * NT + ((j < 4) ? (kx4 + j) : (252 + kx4 + j));
                const float bn = enorm[kidx];
                #pragma unroll
                for (int i = 0; i < 8; ++i) {
                    float A   = znorm_s[m_base + i] + bn;  // rounds at ~256 scale
                    float val = A - 2.0f * acc[i][j];      // 2*acc exact; 1 rounding
                    if (val < bestv[i] || (val == bestv[i] && kidx < besti[i])) {
                        bestv[i] = val; besti[i] = kidx;
                    }
                }
            }
            #pragma unroll
            for (int i = 0; i < 8; ++i)
                #pragma unroll
                for (int j = 0; j < 8; ++j) acc[i][j] = 0.f;
        }
    }

    // ---- argmin reduce across the full wave (64 lanes), lowest index ties ----
    #pragma unroll
    for (int i = 0; i < 8; ++i) {
        float v = bestv[i]; int ix = besti[i];
        #pragma unroll
        for (int off = 32; off; off >>= 1) {
            float ov = __shfl_xor(v, off);
            int   oi = __shfl_xor(ix, off);
            if (ov < v || (ov == v && oi < ix)) { v = ov; ix = oi; }
        }
        if (tx == 0) {
            bestm[m_base + i] = ix;
            out[IDX_OFF + (size_t)blk * MT + m_base + i] = (float)ix;
        }
    }
    __syncthreads();

    // ---- epilogue: gather codebook rows (L2), write z_q coalesced, loss ----
    float lsum = 0.f;
    const size_t zq_base = (size_t)b * D_DIM * HW + p0;
    for (int i2 = t; i2 < D_DIM * MT / 4; i2 += THREADS) {
        int p = i2 & (MT - 1), d4 = i2 >> 6;
        int idx = bestm[p];
        float4 cv = *(const float4*)(cb + (size_t)idx * D_DIM + d4 * 4);
        float z0 = As[(d4 * 4 + 0) * MT + p];
        float z1 = As[(d4 * 4 + 1) * MT + p];
        float z2 = As[(d4 * 4 + 2) * MT + p];
        float z3 = As[(d4 * 4 + 3) * MT + p];
        float e0 = cv.x - z0, e1 = cv.y - z1, e2 = cv.z - z2, e3 = cv.w - z3;
        lsum = fmaf(e0, e0, lsum); lsum = fmaf(e1, e1, lsum);
        lsum = fmaf(e2, e2, lsum); lsum = fmaf(e3, e3, lsum);
        out[zq_base + (size_t)(d4 * 4 + 0) * HW + p] = cv.x;
        out[zq_base + (size_t)(d4 * 4 + 1) * HW + p] = cv.y;
        out[zq_base + (size_t)(d4 * 4 + 2) * HW + p] = cv.z;
        out[zq_base + (size_t)(d4 * 4 + 3) * HW + p] = cv.w;
    }
    #pragma unroll
    for (int off = 32; off; off >>= 1) lsum += __shfl_xor(lsum, off);
    __syncthreads();
    if ((t & 63) == 0) Es[t >> 6] = lsum;
    __syncthreads();
    if (t == 0) {
        float s = 0.f;
        #pragma unroll
        for (int w = 0; w < 8; ++w) s += Es[w];
        atomicAdd(out + LOSS_OFF, s * (1.25f / 8388608.f));
    }
}

extern "C" void kernel_launch(void* const* d_in, const int* in_sizes, int n_in,
                              void* d_out, int out_size, void* d_ws, size_t ws_size,
                              hipStream_t stream) {
    const float* z  = (const float*)d_in[0];
    const float* cb = (const float*)d_in[1];
    float* out = (float*)d_out;
    float* enorm = (float*)d_ws;

    hipMemsetAsync(out + LOSS_OFF, 0, sizeof(float), stream);

    enorm_kernel<<<256, 256, 0, stream>>>(cb, enorm);

    hipFuncSetAttribute((const void*)vq_kernel,
                        hipFuncAttributeMaxDynamicSharedMemorySize, SMEM_BYTES);
    vq_kernel<<<512, THREADS, SMEM_BYTES, stream>>>(z, cb, enorm, out);
}

// Round 6
// 319.148 us; speedup vs baseline: 1.7093x; 1.7093x over previous
//
#include <hip/hip_runtime.h>

// VQ-VAE codebook quantization, MI355X (gfx950)
// z: [32, 256, 32, 32] fp32 ; codebook: [1024, 256] fp32
// outputs (concat fp32): z_q [32,256,32,32] (8388608) | idx [32768] | loss [1]
//
// Correctness contract: idx must match numpy's fp32 argmin of
//   dist = fl( fl(znorm + enorm) - 2*dot ),  ties -> lowest index.
// The +znorm(~256) term quantizes dist to ulp ~3e-5; replicating that
// quantization (NOT dropping the constant term) is what makes ties match.
//
// Resource-allocator map (measured R0-R5, this toolchain):
//   __launch_bounds__(512,2) -> 96-128 VGPR (no spill @ acc[8][8])
//   __launch_bounds__(512,1) / waves_per_eu(2,2) -> 128 (never higher)
//   __launch_bounds__(512,4) -> 64 (catastrophic spill: WRITE 406MB, 530us)
// => 16x8 tile (~212 regs) is unbuildable; 8x8 tile + 128-reg budget it is.
//
// R6 = R5 structure (proven: occupancy 44% = 2 blocks/CU; conflicts 0)
// with the ONE fix: launch_bounds (512,2) restores the 128-reg budget.
//  - MT=64, 512 blocks -> 2 blocks/CU (74240B LDS each, 148480<=160K):
//    4 waves/SIMD of independent TLP hides barriers/staging stalls.
//  - wave-uniform a-reads (broadcast), contiguous 64-lane e-reads
//    (conflict-free), stride-1 staging writes (2/bank, free).
//  - Es single-buffer [4][512], async-split global prefetch between syncs.

#define D_DIM   256
#define K_CODES 1024
#define HW      1024
#define MT      64      // positions per block
#define NT      512     // codes per N-chunk (2 chunks)
#define BK      4       // d-rows staged per step
#define THREADS 512
#define NSTEP   128     // 2 chunks * 64 steps

#define ZQ_OFF   0
#define IDX_OFF  8388608
#define LOSS_OFF 8421376

// As[256][64] + Es[4][512] + znorm_s[64] + bestm[64]
#define SMEM_FLOATS (D_DIM*MT + BK*NT + MT + MT)   // 16384+2048+64+64 = 18560
#define SMEM_BYTES  (SMEM_FLOATS * 4)              // 74240 B ; x2 blocks = 148480 <= 163840

extern __shared__ float smem[];

// ws: enorm[k] = fp32 sum of cb[k][d]^2 (own order; ~ulp(8e-5) agreement is enough)
__global__ void enorm_kernel(const float* __restrict__ cb, float* __restrict__ enorm) {
    int gt = blockIdx.x * blockDim.x + threadIdx.x;
    int k = gt >> 6;
    int lane = gt & 63;
    const float4* row = (const float4*)(cb + (size_t)k * D_DIM);
    float4 v = row[lane];
    float s = fmaf(v.x, v.x, fmaf(v.y, v.y, fmaf(v.z, v.z, v.w * v.w)));
    #pragma unroll
    for (int off = 32; off; off >>= 1) s += __shfl_xor(s, off);
    if (lane == 0) enorm[k] = s;
}

__global__ __launch_bounds__(THREADS, 2)   // empirically: 128-VGPR budget, no spill
void vq_kernel(
        const float* __restrict__ z, const float* __restrict__ cb,
        const float* __restrict__ enorm, float* __restrict__ out)
{
    float* As = smem;                                   // [256][64]
    float* Es = smem + D_DIM * MT;                      // [4][512] (8KB; also znorm scratch)
    float* znorm_s = smem + D_DIM * MT + BK * NT;       // [64]
    int*   bestm   = (int*)(smem + D_DIM * MT + BK * NT + MT); // [64]

    const int t   = threadIdx.x;
    const int blk = blockIdx.x;          // 512 blocks = 2/CU
    const int b   = blk >> 4;
    const int p0  = (blk & 15) * MT;
    const float* zb = z + (size_t)b * D_DIM * HW;

    // staging: thread t stages code (chunk*512 + t), 4 d-values per step.
    const float* cbp = cb + (size_t)t * D_DIM;

    // prologue global load for step g=0 (issued early, hides under znorm)
    float4 sv = *(const float4*)(cbp);

    // ---- stage A^T [256][64] (z read from HBM once, coalesced float4) ----
    for (int i = t; i < D_DIM * MT / 4; i += THREADS) {
        int d = i >> 4, m4 = i & 15;
        *(float4*)(As + d * MT + m4 * 4) = *(const float4*)(zb + d * HW + p0 + m4 * 4);
    }
    __syncthreads();

    // ---- znorm[m] = fp64 sum of As[:,m]^2, rounded to fp32 ----
    // (fp64 vs numpy's pairwise-fp32 differs by <=1-2 ulp of ~256; that's a
    //  uniform exact-ulp shift per row -> argmin invariant.)
    {
        int m = t & (MT - 1), q = t >> 6;            // 8 slices of 32 d
        const float* col = As + m;
        double zp = 0.0;
        #pragma unroll 8
        for (int d = q * 32; d < q * 32 + 32; ++d) {
            double v = (double)col[d * MT];
            zp += v * v;
        }
        double* zscr = (double*)Es;                  // 512 doubles = 4 KB scratch
        zscr[q * MT + m] = zp;
    }
    __syncthreads();
    if (t < MT) {
        double* zscr = (double*)Es;
        double s = 0.0;
        #pragma unroll
        for (int q = 0; q < 8; ++q) s += zscr[q * MT + t];
        znorm_s[t] = (float)s;
    }
    // (first loop barrier below makes znorm_s visible & zscr reads complete
    //  before Es is overwritten by staging)

    // ---- thread layout: wave w owns m rows w*8..+7 (wave-uniform a-reads);
    //      lane tx owns codes {tx*4..+3} u {256+tx*4..+3} of each 512-chunk.
    const int tx = t & 63;
    const int m_base = (t >> 6) * 8;
    const int kx4 = tx * 4;

    float bestv[8]; int besti[8];
    #pragma unroll
    for (int i = 0; i < 8; ++i) { bestv[i] = 3.4e38f; besti[i] = 0; }

    float acc[8][8];
    #pragma unroll
    for (int i = 0; i < 8; ++i)
        #pragma unroll
        for (int j = 0; j < 8; ++j) acc[i][j] = 0.f;

    for (int g = 0; g < NSTEP; ++g) {
        const int c = g >> 6, s = g & 63;

        __syncthreads();                 // readers of previous Es done
        Es[0 * NT + t] = sv.x;           // stride-1 across lanes: 2/bank, free
        Es[1 * NT + t] = sv.y;
        Es[2 * NT + t] = sv.z;
        Es[3 * NT + t] = sv.w;

        // issue next-step global load (L2 latency hides under 4 dd-groups of FMA)
        {
            const int gn = (g < NSTEP - 1) ? g + 1 : NSTEP - 1;
            sv = *(const float4*)(cbp + (((size_t)(gn >> 6)) << 17) + ((gn & 63) << 2));
        }
        __syncthreads();                 // Es visible

        const int dk = s * BK;
        #pragma unroll
        for (int dd = 0; dd < BK; ++dd) {
            const float* Ar = As + (dk + dd) * MT + m_base;   // wave-uniform bcast
            float a[8], e[8];
            *(float4*)(a)     = *(const float4*)(Ar);
            *(float4*)(a + 4) = *(const float4*)(Ar + 4);
            const float* Er = Es + dd * NT + kx4;
            *(float4*)(e)     = *(const float4*)(Er);         // codes kx4..+3
            *(float4*)(e + 4) = *(const float4*)(Er + 256);   // codes 256+kx4..+3
            #pragma unroll
            for (int i = 0; i < 8; ++i)
                #pragma unroll
                for (int j = 0; j < 8; ++j)
                    acc[i][j] = fmaf(a[i], e[j], acc[i][j]);
        }

        if (s == 63) {
            // chunk epilogue: dist = fl( fl(znorm + enorm) - 2*dot ), np-style
            // lane's j=0..3 -> codes c*512+kx4+j ; j=4..7 -> c*512+256+kx4+(j-4)
            #pragma unroll
            for (int j = 0; j < 8; ++j) {
                const int kidx = c * NT + ((j < 4) ? (kx4 + j) : (252 + kx4 + j));
                const float bn = enorm[kidx];
                #pragma unroll
                for (int i = 0; i < 8; ++i) {
                    float A   = znorm_s[m_base + i] + bn;  // rounds at ~256 scale
                    float val = A - 2.0f * acc[i][j];      // 2*acc exact; 1 rounding
                    if (val < bestv[i] || (val == bestv[i] && kidx < besti[i])) {
                        bestv[i] = val; besti[i] = kidx;
                    }
                }
            }
            #pragma unroll
            for (int i = 0; i < 8; ++i)
                #pragma unroll
                for (int j = 0; j < 8; ++j) acc[i][j] = 0.f;
        }
    }

    // ---- argmin reduce across the full wave (64 lanes), lowest index ties ----
    #pragma unroll
    for (int i = 0; i < 8; ++i) {
        float v = bestv[i]; int ix = besti[i];
        #pragma unroll
        for (int off = 32; off; off >>= 1) {
            float ov = __shfl_xor(v, off);
            int   oi = __shfl_xor(ix, off);
            if (ov < v || (ov == v && oi < ix)) { v = ov; ix = oi; }
        }
        if (tx == 0) {
            bestm[m_base + i] = ix;
            out[IDX_OFF + (size_t)blk * MT + m_base + i] = (float)ix;
        }
    }
    __syncthreads();

    // ---- epilogue: gather codebook rows (L2), write z_q coalesced, loss ----
    float lsum = 0.f;
    const size_t zq_base = (size_t)b * D_DIM * HW + p0;
    for (int i2 = t; i2 < D_DIM * MT / 4; i2 += THREADS) {
        int p = i2 & (MT - 1), d4 = i2 >> 6;
        int idx = bestm[p];
        float4 cv = *(const float4*)(cb + (size_t)idx * D_DIM + d4 * 4);
        float z0 = As[(d4 * 4 + 0) * MT + p];
        float z1 = As[(d4 * 4 + 1) * MT + p];
        float z2 = As[(d4 * 4 + 2) * MT + p];
        float z3 = As[(d4 * 4 + 3) * MT + p];
        float e0 = cv.x - z0, e1 = cv.y - z1, e2 = cv.z - z2, e3 = cv.w - z3;
        lsum = fmaf(e0, e0, lsum); lsum = fmaf(e1, e1, lsum);
        lsum = fmaf(e2, e2, lsum); lsum = fmaf(e3, e3, lsum);
        out[zq_base + (size_t)(d4 * 4 + 0) * HW + p] = cv.x;
        out[zq_base + (size_t)(d4 * 4 + 1) * HW + p] = cv.y;
        out[zq_base + (size_t)(d4 * 4 + 2) * HW + p] = cv.z;
        out[zq_base + (size_t)(d4 * 4 + 3) * HW + p] = cv.w;
    }
    #pragma unroll
    for (int off = 32; off; off >>= 1) lsum += __shfl_xor(lsum, off);
    __syncthreads();
    if ((t & 63) == 0) Es[t >> 6] = lsum;
    __syncthreads();
    if (t == 0) {
        float s = 0.f;
        #pragma unroll
        for (int w = 0; w < 8; ++w) s += Es[w];
        atomicAdd(out + LOSS_OFF, s * (1.25f / 8388608.f));
    }
}

extern "C" void kernel_launch(void* const* d_in, const int* in_sizes, int n_in,
                              void* d_out, int out_size, void* d_ws, size_t ws_size,
                              hipStream_t stream) {
    const float* z  = (const float*)d_in[0];
    const float* cb = (const float*)d_in[1];
    float* out = (float*)d_out;
    float* enorm = (float*)d_ws;

    hipMemsetAsync(out + LOSS_OFF, 0, sizeof(float), stream);

    enorm_kernel<<<256, 256, 0, stream>>>(cb, enorm);

    hipFuncSetAttribute((const void*)vq_kernel,
                        hipFuncAttributeMaxDynamicSharedMemorySize, SMEM_BYTES);
    vq_kernel<<<512, THREADS, SMEM_BYTES, stream>>>(z, cb, enorm, out);
}

// Round 7
// 304.261 us; speedup vs baseline: 1.7929x; 1.0489x over previous
//
#include <hip/hip_runtime.h>

// VQ-VAE codebook quantization, MI355X (gfx950)
// z: [32, 256, 32, 32] fp32 ; codebook: [1024, 256] fp32
// outputs (concat fp32): z_q [32,256,32,32] (8388608) | idx [32768] | loss [1]
//
// Correctness contract: idx must match numpy's fp32 argmin of
//   dist = fl( fl(znorm + enorm) - 2*dot ),  ties -> lowest index.
// The +znorm(~256) term quantizes dist to ulp ~3e-5; replicating that
// quantization (NOT dropping the constant term) is what makes ties match.
//
// R7 theory: R1/R6 plateau at 250-270us because the per-CU LDS pipe is the
// binding resource: 16 ds_read_b128 per wave-step (8 a-broadcast + 8 e) =
// 164us total LDS issue > 109us FMA floor. Occupancy can't fix an issue-
// bound pipe. Fix: A-operand is WAVE-UNIFORM -> read it from global z via
// readfirstlane-uniform addresses (scalarizes to s_load; SGPR feeds FMA
// directly). LDS keeps only the codebook tile Es[4][512] (8.7 KB/block):
//  - LDS/wave-step: 8 e-b128 reads + 4 free b32 writes -> ~102us < FMA 109us
//  - tiny LDS -> 2 blocks/CU co-resident (R6's 74KB/block could not fit 2)
//  - znorm + epilogue re-read z from global (coalesced, L2/L3-hot; HBM @2.6%)

#define D_DIM   256
#define K_CODES 1024
#define HW      1024
#define MT      64      // positions per block
#define NT      512     // codes per N-chunk (2 chunks)
#define BK      4       // d-rows staged per step
#define THREADS 512
#define NSTEP   128     // 2 chunks * 64 steps

#define ZQ_OFF   0
#define IDX_OFF  8388608
#define LOSS_OFF 8421376

// Es[4][512] + znorm_s[64] + bestm[64]   (znorm fp64 scratch overlays Es: 4KB<8KB)
#define SMEM_FLOATS (BK*NT + MT + MT)   // 2048+64+64 = 2176
#define SMEM_BYTES  (SMEM_FLOATS * 4)   // 8704 B -> many blocks/CU fit

extern __shared__ float smem[];

// ws: enorm[k] = fp32 sum of cb[k][d]^2 (own order; ~ulp(8e-5) agreement is enough)
__global__ void enorm_kernel(const float* __restrict__ cb, float* __restrict__ enorm) {
    int gt = blockIdx.x * blockDim.x + threadIdx.x;
    int k = gt >> 6;
    int lane = gt & 63;
    const float4* row = (const float4*)(cb + (size_t)k * D_DIM);
    float4 v = row[lane];
    float s = fmaf(v.x, v.x, fmaf(v.y, v.y, fmaf(v.z, v.z, v.w * v.w)));
    #pragma unroll
    for (int off = 32; off; off >>= 1) s += __shfl_xor(s, off);
    if (lane == 0) enorm[k] = s;
}

__global__ __launch_bounds__(THREADS, 2)   // proven: 128-VGPR budget, no spill
void vq_kernel(
        const float* __restrict__ z, const float* __restrict__ cb,
        const float* __restrict__ enorm, float* __restrict__ out)
{
    float* Es      = smem;                        // [4][512] codebook tile
    float* znorm_s = smem + BK * NT;              // [64]
    int*   bestm   = (int*)(smem + BK * NT + MT); // [64]

    const int t   = threadIdx.x;
    const int blk = blockIdx.x;          // 512 blocks = 2/CU of work
    const int b   = blk >> 4;
    const int p0  = (blk & 15) * MT;
    const float* zb = z + (size_t)b * D_DIM * HW;

    // staging: thread t stages code (chunk*512 + t), 4 d-values per step.
    const float* cbp = cb + (size_t)t * D_DIM;

    // prologue global load for step g=0 (issued early, hides under znorm)
    float4 sv = *(const float4*)(cbp);

    // ---- znorm[m] = fp64 sum over d of z[d][p0+m]^2 (global, coalesced) ----
    // wave w handles d-slice [32w, 32w+32); lanes = consecutive m -> coalesced.
    // (fp64 vs numpy's pairwise-fp32 differs by <=1-2 ulp of ~256; uniform
    //  exact-ulp shift per row -> argmin invariant.)
    {
        int m = t & (MT - 1), q = t >> 6;
        const float* col = zb + p0 + m;
        double zp = 0.0;
        #pragma unroll 8
        for (int d = q * 32; d < q * 32 + 32; ++d) {
            double v = (double)col[(size_t)d * HW];
            zp += v * v;
        }
        double* zscr = (double*)Es;                  // 512 doubles = 4 KB scratch
        zscr[q * MT + m] = zp;
    }
    __syncthreads();
    if (t < MT) {
        double* zscr = (double*)Es;
        double s = 0.0;
        #pragma unroll
        for (int q = 0; q < 8; ++q) s += zscr[q * MT + t];
        znorm_s[t] = (float)s;
    }
    // (first loop barrier makes znorm_s visible & zscr reads complete
    //  before Es is overwritten by staging)

    // ---- thread layout: wave w owns m rows w*8..+7 (wave-uniform A);
    //      lane tx owns codes {tx*4..+3} u {256+tx*4..+3} of each 512-chunk.
    const int tx = t & 63;
    const int m_base = (t >> 6) * 8;
    const int kx4 = tx * 4;

    float bestv[8]; int besti[8];
    #pragma unroll
    for (int i = 0; i < 8; ++i) { bestv[i] = 3.4e38f; besti[i] = 0; }

    float acc[8][8];
    #pragma unroll
    for (int i = 0; i < 8; ++i)
        #pragma unroll
        for (int j = 0; j < 8; ++j) acc[i][j] = 0.f;

    for (int g = 0; g < NSTEP; ++g) {
        const int c = g >> 6, s = g & 63;
        const int dk = s * BK;

        // ---- A-operand: wave-uniform scalar loads from global z ----
        // readfirstlane forces the address into SGPRs -> s_load path;
        // issued before the barriers so latency hides under sync + e-reads.
        float a[BK][8];
        #pragma unroll
        for (int dd = 0; dd < BK; ++dd) {
            const int uoff = __builtin_amdgcn_readfirstlane((dk + dd) * HW + p0 + m_base);
            const float* ar = zb + uoff;
            #pragma unroll
            for (int i = 0; i < 8; ++i) a[dd][i] = ar[i];
        }

        __syncthreads();                 // readers of previous Es done
        Es[0 * NT + t] = sv.x;           // stride-1 across lanes: 2/bank, free
        Es[1 * NT + t] = sv.y;
        Es[2 * NT + t] = sv.z;
        Es[3 * NT + t] = sv.w;

        // issue next-step global load (L2 latency hides under FMA block)
        {
            const int gn = (g < NSTEP - 1) ? g + 1 : NSTEP - 1;
            sv = *(const float4*)(cbp + (((size_t)(gn >> 6)) << 17) + ((gn & 63) << 2));
        }
        __syncthreads();                 // Es visible

        #pragma unroll
        for (int dd = 0; dd < BK; ++dd) {
            float e[8];
            const float* Er = Es + dd * NT + kx4;
            *(float4*)(e)     = *(const float4*)(Er);         // codes kx4..+3
            *(float4*)(e + 4) = *(const float4*)(Er + 256);   // codes 256+kx4..+3
            #pragma unroll
            for (int i = 0; i < 8; ++i)
                #pragma unroll
                for (int j = 0; j < 8; ++j)
                    acc[i][j] = fmaf(a[dd][i], e[j], acc[i][j]);
        }

        if (s == 63) {
            // chunk epilogue: dist = fl( fl(znorm + enorm) - 2*dot ), np-style
            // lane's j=0..3 -> codes c*512+kx4+j ; j=4..7 -> c*512+256+kx4+(j-4)
            #pragma unroll
            for (int j = 0; j < 8; ++j) {
                const int kidx = c * NT + ((j < 4) ? (kx4 + j) : (252 + kx4 + j));
                const float bn = enorm[kidx];
                #pragma unroll
                for (int i = 0; i < 8; ++i) {
                    float A   = znorm_s[m_base + i] + bn;  // rounds at ~256 scale
                    float val = A - 2.0f * acc[i][j];      // 2*acc exact; 1 rounding
                    if (val < bestv[i] || (val == bestv[i] && kidx < besti[i])) {
                        bestv[i] = val; besti[i] = kidx;
                    }
                }
            }
            #pragma unroll
            for (int i = 0; i < 8; ++i)
                #pragma unroll
                for (int j = 0; j < 8; ++j) acc[i][j] = 0.f;
        }
    }

    // ---- argmin reduce across the full wave (64 lanes), lowest index ties ----
    #pragma unroll
    for (int i = 0; i < 8; ++i) {
        float v = bestv[i]; int ix = besti[i];
        #pragma unroll
        for (int off = 32; off; off >>= 1) {
            float ov = __shfl_xor(v, off);
            int   oi = __shfl_xor(ix, off);
            if (ov < v || (ov == v && oi < ix)) { v = ov; ix = oi; }
        }
        if (tx == 0) {
            bestm[m_base + i] = ix;
            out[IDX_OFF + (size_t)blk * MT + m_base + i] = (float)ix;
        }
    }
    __syncthreads();

    // ---- epilogue: gather codebook rows (L2), z from global (L2-hot),
    //      write z_q coalesced, loss ----
    float lsum = 0.f;
    const size_t zq_base = (size_t)b * D_DIM * HW + p0;
    for (int i2 = t; i2 < D_DIM * MT / 4; i2 += THREADS) {
        int p = i2 & (MT - 1), d4 = i2 >> 6;
        int idx = bestm[p];
        float4 cv = *(const float4*)(cb + (size_t)idx * D_DIM + d4 * 4);
        const float* zp = zb + p0 + p;
        float z0 = zp[(size_t)(d4 * 4 + 0) * HW];
        float z1 = zp[(size_t)(d4 * 4 + 1) * HW];
        float z2 = zp[(size_t)(d4 * 4 + 2) * HW];
        float z3 = zp[(size_t)(d4 * 4 + 3) * HW];
        float e0 = cv.x - z0, e1 = cv.y - z1, e2 = cv.z - z2, e3 = cv.w - z3;
        lsum = fmaf(e0, e0, lsum); lsum = fmaf(e1, e1, lsum);
        lsum = fmaf(e2, e2, lsum); lsum = fmaf(e3, e3, lsum);
        out[zq_base + (size_t)(d4 * 4 + 0) * HW + p] = cv.x;
        out[zq_base + (size_t)(d4 * 4 + 1) * HW + p] = cv.y;
        out[zq_base + (size_t)(d4 * 4 + 2) * HW + p] = cv.z;
        out[zq_base + (size_t)(d4 * 4 + 3) * HW + p] = cv.w;
    }
    #pragma unroll
    for (int off = 32; off; off >>= 1) lsum += __shfl_xor(lsum, off);
    __syncthreads();
    if ((t & 63) == 0) Es[t >> 6] = lsum;
    __syncthreads();
    if (t == 0) {
        float s = 0.f;
        #pragma unroll
        for (int w = 0; w < 8; ++w) s += Es[w];
        atomicAdd(out + LOSS_OFF, s * (1.25f / 8388608.f));
    }
}

extern "C" void kernel_launch(void* const* d_in, const int* in_sizes, int n_in,
                              void* d_out, int out_size, void* d_ws, size_t ws_size,
                              hipStream_t stream) {
    const float* z  = (const float*)d_in[0];
    const float* cb = (const float*)d_in[1];
    float* out = (float*)d_out;
    float* enorm = (float*)d_ws;

    hipMemsetAsync(out + LOSS_OFF, 0, sizeof(float), stream);

    enorm_kernel<<<256, 256, 0, stream>>>(cb, enorm);

    hipFuncSetAttribute((const void*)vq_kernel,
                        hipFuncAttributeMaxDynamicSharedMemorySize, SMEM_BYTES);
    vq_kernel<<<512, THREADS, SMEM_BYTES, stream>>>(z, cb, enorm, out);
}

// Round 8
// 283.994 us; speedup vs baseline: 1.9209x; 1.0714x over previous
//
#include <hip/hip_runtime.h>

// VQ-VAE codebook quantization, MI355X (gfx950)
// z: [32, 256, 32, 32] fp32 ; codebook: [1024, 256] fp32
// outputs (concat fp32): z_q [32,256,32,32] (8388608) | idx [32768] | loss [1]
//
// Correctness contract: idx must match numpy's fp32 argmin of
//   dist = fl( fl(znorm + enorm) - 2*dot ),  ties -> lowest index.
// The +znorm(~256) term quantizes dist to ulp ~3e-5; replicating that
// quantization (NOT dropping the constant term) is what makes ties match.
//
// R8: R7 (a-operand via wave-uniform s_load, LDS = codebook tile only,
// 2 blocks/CU) proved out at 245us / VALUBusy 59%. Remaining stall is
// step-granularity: 2 barriers/step + write->barrier->read chain + cold
// s_load/ds_read at each step top. This round:
//  - Es double-buffered [2][8][512] (32KB): ONE barrier per step.
//  - BK=8: 512 FMA/thread/step, 64 steps total (half the barriers).
//  - depth-2 cb prefetch: gload(g+2) issued at g, LDS-written at g+1,
//    read at g+2 -> full-step latency cover.
//  - step g writes buf^1 (last read at g-1, safe after g-1's end barrier),
//    computes on buf: single end-of-step barrier is sufficient.

#define D_DIM   256
#define K_CODES 1024
#define HW      1024
#define MT      64      // positions per block
#define NT      512     // codes per N-chunk (2 chunks)
#define BK      8       // d-rows staged per step
#define THREADS 512
#define NSTEP   64      // 2 chunks * 32 steps

#define ZQ_OFF   0
#define IDX_OFF  8388608
#define LOSS_OFF 8421376

// Es[2][8][512] + znorm_s[64] + bestm[64]
#define SMEM_FLOATS (2*BK*NT + MT + MT)   // 8192+128 = 8320
#define SMEM_BYTES  (SMEM_FLOATS * 4)     // 33280 B -> 2+ blocks/CU fit

extern __shared__ float smem[];

// ws: enorm[k] = fp32 sum of cb[k][d]^2 (own order; ~ulp(8e-5) agreement is enough)
__global__ void enorm_kernel(const float* __restrict__ cb, float* __restrict__ enorm) {
    int gt = blockIdx.x * blockDim.x + threadIdx.x;
    int k = gt >> 6;
    int lane = gt & 63;
    const float4* row = (const float4*)(cb + (size_t)k * D_DIM);
    float4 v = row[lane];
    float s = fmaf(v.x, v.x, fmaf(v.y, v.y, fmaf(v.z, v.z, v.w * v.w)));
    #pragma unroll
    for (int off = 32; off; off >>= 1) s += __shfl_xor(s, off);
    if (lane == 0) enorm[k] = s;
}

__global__ __launch_bounds__(THREADS, 2)   // proven: <=128-VGPR budget, no spill
void vq_kernel(
        const float* __restrict__ z, const float* __restrict__ cb,
        const float* __restrict__ enorm, float* __restrict__ out)
{
    float* Es      = smem;                            // [2][8][512] codebook dbuf
    float* znorm_s = smem + 2 * BK * NT;              // [64]
    int*   bestm   = (int*)(smem + 2 * BK * NT + MT); // [64]

    const int t   = threadIdx.x;
    const int blk = blockIdx.x;          // 512 blocks = 2/CU
    const int b   = blk >> 4;
    const int p0  = (blk & 15) * MT;
    const float* zb = z + (size_t)b * D_DIM * HW;

    // staging: thread t stages code (chunk*512 + t), 8 d-values per step.
    const float* cbp = cb + (size_t)t * D_DIM;

    // gload step 0 early (hides under znorm)
    float4 s0a = *(const float4*)(cbp);
    float4 s0b = *(const float4*)(cbp + 4);

    // ---- znorm[m] = fp64 sum over d of z[d][p0+m]^2 (global, coalesced) ----
    // (fp64 vs numpy's pairwise-fp32 differs by <=1-2 ulp of ~256; uniform
    //  exact-ulp shift per row -> argmin invariant.)
    {
        int m = t & (MT - 1), q = t >> 6;
        const float* col = zb + p0 + m;
        double zp = 0.0;
        #pragma unroll 8
        for (int d = q * 32; d < q * 32 + 32; ++d) {
            double v = (double)col[(size_t)d * HW];
            zp += v * v;
        }
        double* zscr = (double*)Es;                  // 512 doubles = 4 KB scratch
        zscr[q * MT + m] = zp;
    }
    __syncthreads();
    if (t < MT) {
        double* zscr = (double*)Es;
        double s = 0.0;
        #pragma unroll
        for (int q = 0; q < 8; ++q) s += zscr[q * MT + t];
        znorm_s[t] = (float)s;
    }
    __syncthreads();   // zscr reads done before buf0 staging overwrites them

    // ---- stage step 0 into buf0; issue gload step 1 ----
    {
        Es[0 * NT + t] = s0a.x;  Es[1 * NT + t] = s0a.y;
        Es[2 * NT + t] = s0a.z;  Es[3 * NT + t] = s0a.w;
        Es[4 * NT + t] = s0b.x;  Es[5 * NT + t] = s0b.y;
        Es[6 * NT + t] = s0b.z;  Es[7 * NT + t] = s0b.w;
    }
    float4 svA = *(const float4*)(cbp + BK);        // step 1 data
    float4 svB = *(const float4*)(cbp + BK + 4);
    __syncthreads();   // buf0 visible

    // ---- thread layout: wave w owns m rows w*8..+7 (wave-uniform A);
    //      lane tx owns codes {tx*4..+3} u {256+tx*4..+3} of each 512-chunk.
    const int tx = t & 63;
    const int m_base = (t >> 6) * 8;
    const int kx4 = tx * 4;

    float bestv[8]; int besti[8];
    #pragma unroll
    for (int i = 0; i < 8; ++i) { bestv[i] = 3.4e38f; besti[i] = 0; }

    float acc[8][8];
    #pragma unroll
    for (int i = 0; i < 8; ++i)
        #pragma unroll
        for (int j = 0; j < 8; ++j) acc[i][j] = 0.f;

    int cur = 0;
    for (int g = 0; g < NSTEP; ++g) {
        // write step g+1 data into buf^1 (its last readers finished at g-1)
        if (g < NSTEP - 1) {
            float* En = Es + (cur ^ 1) * (BK * NT);
            En[0 * NT + t] = svA.x;  En[1 * NT + t] = svA.y;
            En[2 * NT + t] = svA.z;  En[3 * NT + t] = svA.w;
            En[4 * NT + t] = svB.x;  En[5 * NT + t] = svB.y;
            En[6 * NT + t] = svB.z;  En[7 * NT + t] = svB.w;
        }
        // issue gload for step g+2 (consumed as LDS-write at g+1)
        {
            const int gn = (g + 2 < NSTEP) ? g + 2 : NSTEP - 1;
            const float* p = cbp + (((size_t)(gn >> 5)) << 17) + ((gn & 31) << 3);
            svA = *(const float4*)(p);
            svB = *(const float4*)(p + 4);
        }

        const int dk = (g & 31) * BK;
        const float* Ec = Es + cur * (BK * NT);
        #pragma unroll
        for (int dd = 0; dd < BK; ++dd) {
            // A-operand: wave-uniform scalar loads from global z (s_load path)
            const int uoff = __builtin_amdgcn_readfirstlane((dk + dd) * HW + p0 + m_base);
            const float* ar = zb + uoff;
            float e[8];
            const float* Er = Ec + dd * NT + kx4;
            *(float4*)(e)     = *(const float4*)(Er);         // codes kx4..+3
            *(float4*)(e + 4) = *(const float4*)(Er + 256);   // codes 256+kx4..+3
            #pragma unroll
            for (int i = 0; i < 8; ++i)
                #pragma unroll
                for (int j = 0; j < 8; ++j)
                    acc[i][j] = fmaf(ar[i], e[j], acc[i][j]);
        }

        if ((g & 31) == 31) {
            // chunk epilogue: dist = fl( fl(znorm + enorm) - 2*dot ), np-style
            const int c = g >> 5;
            #pragma unroll
            for (int j = 0; j < 8; ++j) {
                const int kidx = c * NT + ((j < 4) ? (kx4 + j) : (252 + kx4 + j));
                const float bn = enorm[kidx];
                #pragma unroll
                for (int i = 0; i < 8; ++i) {
                    float A   = znorm_s[m_base + i] + bn;  // rounds at ~256 scale
                    float val = A - 2.0f * acc[i][j];      // 2*acc exact; 1 rounding
                    if (val < bestv[i] || (val == bestv[i] && kidx < besti[i])) {
                        bestv[i] = val; besti[i] = kidx;
                    }
                }
            }
            #pragma unroll
            for (int i = 0; i < 8; ++i)
                #pragma unroll
                for (int j = 0; j < 8; ++j) acc[i][j] = 0.f;
        }
        __syncthreads();
        cur ^= 1;
    }

    // ---- argmin reduce across the full wave (64 lanes), lowest index ties ----
    #pragma unroll
    for (int i = 0; i < 8; ++i) {
        float v = bestv[i]; int ix = besti[i];
        #pragma unroll
        for (int off = 32; off; off >>= 1) {
            float ov = __shfl_xor(v, off);
            int   oi = __shfl_xor(ix, off);
            if (ov < v || (ov == v && oi < ix)) { v = ov; ix = oi; }
        }
        if (tx == 0) {
            bestm[m_base + i] = ix;
            out[IDX_OFF + (size_t)blk * MT + m_base + i] = (float)ix;
        }
    }
    __syncthreads();

    // ---- epilogue: gather codebook rows (L2), z from global (L2-hot),
    //      write z_q coalesced, loss ----
    float lsum = 0.f;
    const size_t zq_base = (size_t)b * D_DIM * HW + p0;
    for (int i2 = t; i2 < D_DIM * MT / 4; i2 += THREADS) {
        int p = i2 & (MT - 1), d4 = i2 >> 6;
        int idx = bestm[p];
        float4 cv = *(const float4*)(cb + (size_t)idx * D_DIM + d4 * 4);
        const float* zp = zb + p0 + p;
        float z0 = zp[(size_t)(d4 * 4 + 0) * HW];
        float z1 = zp[(size_t)(d4 * 4 + 1) * HW];
        float z2 = zp[(size_t)(d4 * 4 + 2) * HW];
        float z3 = zp[(size_t)(d4 * 4 + 3) * HW];
        float e0 = cv.x - z0, e1 = cv.y - z1, e2 = cv.z - z2, e3 = cv.w - z3;
        lsum = fmaf(e0, e0, lsum); lsum = fmaf(e1, e1, lsum);
        lsum = fmaf(e2, e2, lsum); lsum = fmaf(e3, e3, lsum);
        out[zq_base + (size_t)(d4 * 4 + 0) * HW + p] = cv.x;
        out[zq_base + (size_t)(d4 * 4 + 1) * HW + p] = cv.y;
        out[zq_base + (size_t)(d4 * 4 + 2) * HW + p] = cv.z;
        out[zq_base + (size_t)(d4 * 4 + 3) * HW + p] = cv.w;
    }
    #pragma unroll
    for (int off = 32; off; off >>= 1) lsum += __shfl_xor(lsum, off);
    __syncthreads();
    if ((t & 63) == 0) Es[t >> 6] = lsum;
    __syncthreads();
    if (t == 0) {
        float s = 0.f;
        #pragma unroll
        for (int w = 0; w < 8; ++w) s += Es[w];
        atomicAdd(out + LOSS_OFF, s * (1.25f / 8388608.f));
    }
}

extern "C" void kernel_launch(void* const* d_in, const int* in_sizes, int n_in,
                              void* d_out, int out_size, void* d_ws, size_t ws_size,
                              hipStream_t stream) {
    const float* z  = (const float*)d_in[0];
    const float* cb = (const float*)d_in[1];
    float* out = (float*)d_out;
    float* enorm = (float*)d_ws;

    hipMemsetAsync(out + LOSS_OFF, 0, sizeof(float), stream);

    enorm_kernel<<<256, 256, 0, stream>>>(cb, enorm);

    hipFuncSetAttribute((const void*)vq_kernel,
                        hipFuncAttributeMaxDynamicSharedMemorySize, SMEM_BYTES);
    vq_kernel<<<512, THREADS, SMEM_BYTES, stream>>>(z, cb, enorm, out);
}